// Round 1
// baseline (469.959 us; speedup 1.0000x reference)
//
#include <hip/hip_runtime.h>

#define H 128
#define EPS 1e-5f
#define NPB 256      // nodes per bucket (pow2); bucket = node >> 8

typedef __attribute__((ext_vector_type(8))) short bf16x8;
typedef __attribute__((ext_vector_type(4))) float f32x4;

__device__ inline unsigned short f2bf(float f){
  unsigned int u=__float_as_uint(f);
  return (unsigned short)((u + 0x7FFFu + ((u>>16)&1u))>>16);
}
__device__ inline unsigned int pack_bf16(float a, float b){
  unsigned int ua=__float_as_uint(a), ub=__float_as_uint(b);
  ua = (ua + 0x7FFFu + ((ua>>16)&1u)) >> 16;
  ub = (ub + 0x7FFFu + ((ub>>16)&1u)) & 0xFFFF0000u;
  return ua | ub;
}
__device__ inline float bflo(unsigned int u){ return __uint_as_float(u<<16); }
__device__ inline float bfhi(unsigned int u){ return __uint_as_float(u&0xFFFF0000u); }

// ============ CSR build via 2-level bucket sort ============
// Bucket = dest>>8. Binning writes land in per-block contiguous runs; final placement
// scatters only inside a ~32KB bucket window (L1/L2-resident). deg/dnorm/rowptr derived
// per bucket in LDS. pairs value carries ew*dnorm[row].

// ---- bucket histogram (block-local LDS, then 1 atomic per bucket) ----
__global__ __launch_bounds__(256) void k_bcount(const int* __restrict__ col, int E,
                                                int* __restrict__ bcnt){
  __shared__ int h[512];
  int t=threadIdx.x;
  for(int i=t;i<512;i+=256) h[i]=0;
  __syncthreads();
  int e0=blockIdx.x*4096, e1=min(e0+4096,E);
  for(int e=e0+t;e<e1;e+=256) atomicAdd(&h[((unsigned)col[e])>>8],1);
  __syncthreads();
  for(int i=t;i<512;i+=256) if(h[i]) atomicAdd(&bcnt[i],h[i]);
}

// ---- exclusive scan of bucket counts (single block) ----
__global__ void k_bscan(const int* __restrict__ bcnt, int B, int E,
                        int* __restrict__ bbase, int* __restrict__ cursor){
  __shared__ int s[512];
  int t=threadIdx.x;
  int v=(t<B)?bcnt[t]:0;
  s[t]=v; __syncthreads();
  for(int off=1;off<512;off<<=1){ int u=(t>=off)?s[t-off]:0; __syncthreads(); s[t]+=u; __syncthreads(); }
  if(t<B){ bbase[t]=s[t]-v; cursor[t]=s[t]-v; }
  if(t==0) bbase[B]=E;
}

// ---- binning: stg[...] = (local<<24 | row, ew), grouped by bucket ----
__global__ __launch_bounds__(256) void k_bfill(const int* __restrict__ row, const int* __restrict__ col,
    const float* __restrict__ ew, int E, int* __restrict__ cursor, uint2* __restrict__ stg){
  __shared__ int h[512];
  __shared__ int ofs[512];
  int t=threadIdx.x;
  for(int i=t;i<512;i+=256) h[i]=0;
  __syncthreads();
  int e0=blockIdx.x*4096, e1=min(e0+4096,E);
  for(int e=e0+t;e<e1;e+=256) atomicAdd(&h[((unsigned)col[e])>>8],1);
  __syncthreads();
  for(int i=t;i<512;i+=256) ofs[i] = h[i] ? atomicAdd(&cursor[i],h[i]) : 0;
  __syncthreads();
  for(int i=t;i<512;i+=256) h[i]=0;
  __syncthreads();
  for(int e=e0+t;e<e1;e+=256){
    unsigned d=(unsigned)col[e];
    int b=d>>8;
    int lp=atomicAdd(&h[b],1);
    stg[ofs[b]+lp]=make_uint2(((d&255u)<<24)|(unsigned)row[e], __float_as_uint(ew[e]));
  }
}

// ---- per-bucket: degree -> dnorm + rowptr (LDS count + scan) ----
__global__ __launch_bounds__(256) void k_p2a(const uint2* __restrict__ stg, const int* __restrict__ bbase,
    int N, int E, float* __restrict__ dnorm, int* __restrict__ rowptr){
  __shared__ int cnt[256];
  __shared__ int pre[256];
  int b=blockIdx.x, t=threadIdx.x;
  cnt[t]=0; __syncthreads();
  int s0=bbase[b], s1=bbase[b+1];
  for(int p=s0+t;p<s1;p+=256) atomicAdd(&cnt[stg[p].x>>24],1);
  __syncthreads();
  int v=cnt[t];
  pre[t]=v; __syncthreads();
  for(int off=1;off<256;off<<=1){ int u=(t>=off)?pre[t-off]:0; __syncthreads(); pre[t]+=u; __syncthreads(); }
  int node=(b<<8)+t;
  if(node<N){
    dnorm[node]= v>0 ? rsqrtf((float)v) : 0.f;   // nan_to_num: deg==0 -> coefficient 0
    rowptr[node]=s0+pre[t]-v;
    if(node==N-1) rowptr[N]=E;
  }
}

// ---- per-bucket: place records -> pairs, folding dnorm[row] into the value ----
__global__ __launch_bounds__(256) void k_p2b(const uint2* __restrict__ stg, const int* __restrict__ bbase,
    int N, const int* __restrict__ rowptr, const float* __restrict__ dnorm,
    float2* __restrict__ pairs){
  __shared__ int cur[256];
  int b=blockIdx.x, t=threadIdx.x;
  int node=(b<<8)+t;
  cur[t]=(node<N)?rowptr[node]:0;
  __syncthreads();
  int s0=bbase[b], s1=bbase[b+1];
  for(int p=s0+t;p<s1;p+=256){
    uint2 rec=stg[p];
    int r=(int)(rec.x&0xFFFFFFu);
    int pos=atomicAdd(&cur[rec.x>>24],1);
    pairs[pos]=make_float2(__int_as_float(r), __uint_as_float(rec.y)*dnorm[r]);
  }
}

// ---------------- SpMM bf16 v10: wave/dest, quarter-wave gathers ----------------
// Quarter q = lane>>4 handles edge (p + j*4 + q); ln = lane&15 reads 16B (8 ch) of
// the 256B row -> one dwordx4 gather instruction covers 4 edges (addr VALU /4).
// Unpack/BN/FMA lane-work conserved. Tail = ONE masked 4-gather batch (uniform group
// guards + weight-zeroed clamped loads) so all remaining gathers issue together --
// removes the serial-latency tail for deg<16 dests. Cross-quarter reduce = 2 shfl_xor;
// q==0 lanes store 16B each (256B coalesced).
// BN0 applies stage-0 BN+ReLU inline to each gathered value (gather source = raw z0).
template<bool BN0>
__global__ __launch_bounds__(256) void k_spmm_bf(const float2* __restrict__ pairs,
    const int* __restrict__ rowptr, const float* __restrict__ dnorm,
    const unsigned short* __restrict__ hb, unsigned short* __restrict__ zb, int N,
    const float* __restrict__ bnst, const float* __restrict__ gamma,
    const float* __restrict__ beta, float invN){
  int wid=(blockIdx.x*256+threadIdx.x)>>6;
  int lane=threadIdx.x&63;
  if(wid>=N) return;
  int q  = lane>>4;          // edge slot within group-of-4
  int ln = lane&15;          // channel block: ch [ln*8, ln*8+8)
  int lnoff = ln<<4;         // byte offset into row

  float sc[8], sh[8];
  if(BN0){
    int c0=ln<<3;
    #pragma unroll
    for(int i=0;i<8;i++){
      float m = bnst[c0+i]*invN;
      float v = bnst[128+c0+i]*invN - m*m;
      float s = rsqrtf(v+EPS)*gamma[c0+i];
      sc[i]=s; sh[i]=beta[c0+i]-m*s;
    }
  }

  int beg=__builtin_amdgcn_readfirstlane(rowptr[wid]);
  int end=__builtin_amdgcn_readfirstlane(rowptr[wid+1]);

  float acc[8];
  #pragma unroll
  for(int i=0;i<8;i++) acc[i]=0.f;

  const uint2* pp=(const uint2*)pairs;
  const char*  hB=(const char*)hb;

  int p=beg;
  // -------- unmasked batches of 16 edges (4 gathers in flight) --------
  for(; p+16<=end; p+=16){
    uint2 pr[4]; uint4 u[4];
    #pragma unroll
    for(int j=0;j<4;j++) pr[j]=pp[p + j*4 + q];
    #pragma unroll
    for(int j=0;j<4;j++)
      u[j]=*(const uint4*)(hB + (((size_t)pr[j].x)<<8) + lnoff);
    #pragma unroll
    for(int j=0;j<4;j++){
      float w=__uint_as_float(pr[j].y);
      float f[8];
      f[0]=bflo(u[j].x); f[1]=bfhi(u[j].x);
      f[2]=bflo(u[j].y); f[3]=bfhi(u[j].y);
      f[4]=bflo(u[j].z); f[5]=bfhi(u[j].z);
      f[6]=bflo(u[j].w); f[7]=bfhi(u[j].w);
      #pragma unroll
      for(int i=0;i<8;i++){
        float v=f[i];
        if(BN0) v=fmaxf(fmaf(v,sc[i],sh[i]),0.f);
        acc[i]=fmaf(w,v,acc[i]);
      }
    }
  }
  // -------- masked tail: ONE batch, all gathers issue together --------
  if(p<end){
    uint2 pr[4]; uint4 u[4];
    #pragma unroll
    for(int j=0;j<4;j++){
      if(p+j*4<end){                       // wave-uniform group guard
        int e=p+j*4+q;
        uint2 t=pp[min(e,end-1)];          // clamped: always a valid record
        pr[j].x=t.x;
        pr[j].y=(e<end)?t.y:0u;            // weight 0 for padded lanes
      }
    }
    #pragma unroll
    for(int j=0;j<4;j++)
      if(p+j*4<end)
        u[j]=*(const uint4*)(hB + (((size_t)pr[j].x)<<8) + lnoff);
    #pragma unroll
    for(int j=0;j<4;j++){
      if(p+j*4<end){
        float w=__uint_as_float(pr[j].y);
        float f[8];
        f[0]=bflo(u[j].x); f[1]=bfhi(u[j].x);
        f[2]=bflo(u[j].y); f[3]=bfhi(u[j].y);
        f[4]=bflo(u[j].z); f[5]=bfhi(u[j].z);
        f[6]=bflo(u[j].w); f[7]=bfhi(u[j].w);
        #pragma unroll
        for(int i=0;i<8;i++){
          float v=f[i];
          if(BN0) v=fmaxf(fmaf(v,sc[i],sh[i]),0.f);
          acc[i]=fmaf(w,v,acc[i]);
        }
      }
    }
  }

  // -------- reduce quarters: lanes {ln, ln+16, ln+32, ln+48} --------
  #pragma unroll
  for(int i=0;i<8;i++){
    acc[i] += __shfl_xor(acc[i],16);
    acc[i] += __shfl_xor(acc[i],32);
  }
  if(q==0){
    float dn=dnorm[wid];
    uint4 o;
    o.x=pack_bf16(acc[0]*dn,acc[1]*dn);
    o.y=pack_bf16(acc[2]*dn,acc[3]*dn);
    o.z=pack_bf16(acc[4]*dn,acc[5]*dn);
    o.w=pack_bf16(acc[6]*dn,acc[7]*dn);
    *(uint4*)(zb + ((size_t)wid<<7) + (ln<<3)) = o;
  }
}

// ---------------- MFMA GEMM (N x 128 @ 128 x 128) + fused BN sum/sumsq ----------------
// bf16 MFMA 16x16x32. Wave = 64 rows x 128 cols (4 row-tiles x 8 ntiles, K = 4x32).
// W staged once/block into LDS transposed bf16 (pitch 136). A-frags straight from
// global (16B/lane). In-place safe. Layouts: A m=lane&15,k=quad*8+j; C/D col=lane&15,
// row=quad*4+reg [m89/m120-verified].
template<bool F32A>
__global__ __launch_bounds__(256,2) void k_gemm_bn(const void* __restrict__ Ap,
    const float* __restrict__ W, const float* __restrict__ bias,
    unsigned short* __restrict__ Zb, float* __restrict__ stats, int N){
  __shared__ __align__(16) unsigned short sWT[128*136];   // 34816 B
  int t=threadIdx.x;

  for(int it=t; it<4096; it+=256){
    float4 v=((const float4*)W)[it];
    int lin=it*4; int k=lin>>7; int c0=lin&127;
    sWT[(c0+0)*136+k]=f2bf(v.x);
    sWT[(c0+1)*136+k]=f2bf(v.y);
    sWT[(c0+2)*136+k]=f2bf(v.z);
    sWT[(c0+3)*136+k]=f2bf(v.w);
  }
  __syncthreads();

  int w=t>>6, lane=t&63, n=lane&15, quad=lane>>4;
  int r0w = blockIdx.x*256 + w*64;

  f32x4 acc[8][4];
  #pragma unroll
  for(int nt=0;nt<8;nt++)
    #pragma unroll
    for(int rt=0;rt<4;rt++){ f32x4 z4={0.f,0.f,0.f,0.f}; acc[nt][rt]=z4; }

  #pragma unroll
  for(int ks=0; ks<4; ks++){
    int k0 = ks*32 + quad*8;
    bf16x8 a[4];
    #pragma unroll
    for(int rt=0;rt<4;rt++){
      int r = r0w + rt*16 + n;
      bf16x8 af={0,0,0,0,0,0,0,0};
      if(r<N){
        if(F32A){
          const float* Af=(const float*)Ap;
          float4 u0=*(const float4*)&Af[(size_t)r*128 + k0];
          float4 u1=*(const float4*)&Af[(size_t)r*128 + k0 + 4];
          af[0]=(short)f2bf(u0.x); af[1]=(short)f2bf(u0.y);
          af[2]=(short)f2bf(u0.z); af[3]=(short)f2bf(u0.w);
          af[4]=(short)f2bf(u1.x); af[5]=(short)f2bf(u1.y);
          af[6]=(short)f2bf(u1.z); af[7]=(short)f2bf(u1.w);
        }else{
          af = *(const bf16x8*)((const unsigned short*)Ap + (size_t)r*128 + k0);
        }
      }
      a[rt]=af;
    }
    #pragma unroll
    for(int nt=0;nt<8;nt++){
      bf16x8 b = *(const bf16x8*)&sWT[(nt*16+n)*136 + k0];
      #pragma unroll
      for(int rt=0;rt<4;rt++)
        acc[nt][rt]=__builtin_amdgcn_mfma_f32_16x16x32_bf16(a[rt], b, acc[nt][rt], 0,0,0);
    }
  }

  __syncthreads();                        // reuse sWT for stats partials
  float* sS=(float*)sWT;                  // [16][132]
  float* sQ=sS + 16*132;                  // [16][132]
  #pragma unroll
  for(int nt=0;nt<8;nt++){
    int c=nt*16+n;
    float bc=bias[c];
    float s=0.f,q=0.f;
    #pragma unroll
    for(int rt=0;rt<4;rt++){
      #pragma unroll
      for(int i=0;i<4;i++){
        int r=r0w + rt*16 + quad*4 + i;
        if(r<N){
          float z=acc[nt][rt][i]+bc;
          Zb[(size_t)r*128+c]=f2bf(z);
          s+=z; q+=z*z;
        }
      }
    }
    sS[(w*4+quad)*132+c]=s;
    sQ[(w*4+quad)*132+c]=q;
  }
  __syncthreads();
  if(t<128){
    float s=0.f,q=0.f;
    #pragma unroll
    for(int g=0;g<16;g++){ s+=sS[g*132+t]; q+=sQ[g*132+t]; }
    atomicAdd(&stats[t],s); atomicAdd(&stats[128+t],q);
  }
}

// ---------------- apply: BN finalize (in-block) + scale/shift + ReLU + residual ----------------
// BNRES: residual operand is raw z0 -> apply stage-0 BN+ReLU inline (h0 never
// materialized). smi[0:256)=this stage scale/shift, smi[256:512)=residual stage's.
template<bool OUTF32, bool BNRES>
__global__ __launch_bounds__(256) void k_apply(const unsigned short* __restrict__ Zb,
    const float* __restrict__ stats, const float* __restrict__ gamma,
    const float* __restrict__ beta, float invN,
    const unsigned short* __restrict__ res,
    const float* __restrict__ rstats, const float* __restrict__ rgamma,
    const float* __restrict__ rbeta,
    float* __restrict__ outf, unsigned short* __restrict__ outb, int n4){
  __shared__ float smi[512];
  int t=threadIdx.x;
  if(t<128){
    float mean=stats[t]*invN;
    float var=stats[128+t]*invN - mean*mean;
    float sc=rsqrtf(var+EPS)*gamma[t];
    smi[t]=sc; smi[128+t]=beta[t]-mean*sc;
    if(BNRES){
      float rm=rstats[t]*invN;
      float rv=rstats[128+t]*invN - rm*rm;
      float rs=rsqrtf(rv+EPS)*rgamma[t];
      smi[256+t]=rs; smi[384+t]=rbeta[t]-rm*rs;
    }
  }
  __syncthreads();
  int i=blockIdx.x*256+t;
  if(i>=n4) return;
  int c=(i&31)*4;
  uint2 zu=((const uint2*)Zb)[i];
  float4 z;
  z.x=bflo(zu.x); z.y=bfhi(zu.x);
  z.z=bflo(zu.y); z.w=bfhi(zu.y);
  float4 sc=*(const float4*)&smi[c];
  float4 sh=*(const float4*)&smi[128+c];
  float4 o;
  o.x=fmaxf(fmaf(z.x,sc.x,sh.x),0.f);
  o.y=fmaxf(fmaf(z.y,sc.y,sh.y),0.f);
  o.z=fmaxf(fmaf(z.z,sc.z,sh.z),0.f);
  o.w=fmaxf(fmaf(z.w,sc.w,sh.w),0.f);
  if(res){
    uint2 ru=((const uint2*)res)[i];
    float4 r;
    r.x=bflo(ru.x); r.y=bfhi(ru.x);
    r.z=bflo(ru.y); r.w=bfhi(ru.y);
    if(BNRES){
      float4 rs=*(const float4*)&smi[256+c];
      float4 rh=*(const float4*)&smi[384+c];
      r.x=fmaxf(fmaf(r.x,rs.x,rh.x),0.f);
      r.y=fmaxf(fmaf(r.y,rs.y,rh.y),0.f);
      r.z=fmaxf(fmaf(r.z,rs.z,rh.z),0.f);
      r.w=fmaxf(fmaf(r.w,rs.w,rh.w),0.f);
    }
    o.x+=r.x; o.y+=r.y; o.z+=r.z; o.w+=r.w;
  }
  if(OUTF32){
    ((float4*)outf)[i]=o;
  }else{
    uint2 pk; pk.x=pack_bf16(o.x,o.y); pk.y=pack_bf16(o.z,o.w);
    ((uint2*)outb)[i]=pk;
  }
}

extern "C" void kernel_launch(void* const* d_in, const int* in_sizes, int n_in,
                              void* d_out, int out_size, void* d_ws, size_t ws_size,
                              hipStream_t stream){
  const float* x      = (const float*)d_in[0];
  const int*   ei     = (const int*)  d_in[1];
  const float* ew     = (const float*)d_in[2];
  const float* fc_w   = (const float*)d_in[3];
  const float* fc_b   = (const float*)d_in[4];
  const float* conv_w = (const float*)d_in[5];
  const float* conv_b = (const float*)d_in[6];
  const float* gamma  = (const float*)d_in[7];
  const float* beta   = (const float*)d_in[8];
  float* out = (float*)d_out;

  int N = in_sizes[0]/H;
  int E = in_sizes[2];
  const int* row = ei;
  const int* col = ei + E;
  int B = (N+NPB-1)/NPB;                 // buckets

  // workspace layout (~78 MB)
  size_t NH = (size_t)N*H;
  unsigned short* zb   = (unsigned short*)d_ws;  // N*H bf16: z0, then h1
  unsigned short* hbuf = zb + NH;                // N*H bf16: agg / z1 / z2
  uint2*  stg    = (uint2*)(hbuf + NH);          // E bucket-grouped records
  float2* pairs  = (float2*)(stg + E);           // E final CSR records (val = ew*dnorm[row])
  float*  stats  = (float*)(pairs + E);          // 3*256   } contiguous for
  int*    bcnt   = (int*)(stats + 768);          // 512     } single memset
  int*    bbase  = bcnt + 512;                   // 513
  int*    cursor = bbase + 513;                  // 512
  float*  dnorm  = (float*)(cursor + 512);       // N
  int*    rowptr = (int*)(dnorm + N);            // N+1

  hipMemsetAsync(stats, 0, sizeof(float)*(768+512), stream);

  int gE4k = (E+4095)/4096;
  k_bcount<<<gE4k,256,0,stream>>>(col,E,bcnt);
  k_bscan<<<1,512,0,stream>>>(bcnt,B,E,bbase,cursor);
  k_bfill<<<gE4k,256,0,stream>>>(row,col,ew,E,cursor,stg);
  k_p2a<<<B,256,0,stream>>>(stg,bbase,N,E,dnorm,rowptr);
  k_p2b<<<B,256,0,stream>>>(stg,bbase,N,rowptr,dnorm,pairs);

  int GB=(N+255)/256;
  int gApply=((N*32)+255)/256;
  int gSpmm=(N+3)/4;
  float invN=1.f/(float)N;

  // stage 0: z0 = x @ fc_w + fc_b  -> zb (h0 = relu(bn0(z0)) is NEVER materialized)
  k_gemm_bn<true><<<GB,256,0,stream>>>(x, fc_w, fc_b, zb, stats, N);

  // layer 0: agg = A_hat @ relu(bn0(z0))  [BN0 inline in gather]  -> hbuf
  k_spmm_bf<true><<<gSpmm,256,0,stream>>>(pairs,rowptr,dnorm, zb, hbuf, N,
                                          stats, gamma, beta, invN);
  k_gemm_bn<false><<<GB,256,0,stream>>>(hbuf, conv_w, conv_b, hbuf, stats+256, N);
  // h1 = relu(bn1(z1)) + relu(bn0(z0))  -> zb (in-place over z0)
  k_apply<false,true><<<gApply,256,0,stream>>>(hbuf, stats+256, gamma+H, beta+H, invN,
                                               zb, stats, gamma, beta,
                                               nullptr, zb, N*32);

  // layer 1: out = relu(bn2(agg(h1) @ W1 + b1)) + h1 -> fp32 d_out
  k_spmm_bf<false><<<gSpmm,256,0,stream>>>(pairs,rowptr,dnorm, zb, hbuf, N,
                                           nullptr, nullptr, nullptr, 0.f);
  k_gemm_bn<false><<<GB,256,0,stream>>>(hbuf, conv_w + (size_t)H*H, conv_b + H, hbuf, stats+512, N);
  k_apply<true,false><<<gApply,256,0,stream>>>(hbuf, stats+512, gamma+2*H, beta+2*H, invN,
                                               zb, nullptr, nullptr, nullptr,
                                               out, nullptr, N*32);
}

// Round 3
// 466.045 us; speedup vs baseline: 1.0084x; 1.0084x over previous
//
#include <hip/hip_runtime.h>

#define H 128
#define EPS 1e-5f
#define NPB 256      // nodes per bucket (pow2); bucket = node >> 8

typedef __attribute__((ext_vector_type(8))) short bf16x8;
typedef __attribute__((ext_vector_type(4))) float f32x4;

__device__ inline unsigned short f2bf(float f){
  unsigned int u=__float_as_uint(f);
  return (unsigned short)((u + 0x7FFFu + ((u>>16)&1u))>>16);
}
__device__ inline unsigned int pack_bf16(float a, float b){
  unsigned int ua=__float_as_uint(a), ub=__float_as_uint(b);
  ua = (ua + 0x7FFFu + ((ua>>16)&1u)) >> 16;
  ub = (ub + 0x7FFFu + ((ub>>16)&1u)) & 0xFFFF0000u;
  return ua | ub;
}
__device__ inline float bflo(unsigned int u){ return __uint_as_float(u<<16); }
__device__ inline float bfhi(unsigned int u){ return __uint_as_float(u&0xFFFF0000u); }

// ============ CSR build via 2-level bucket sort ============
// Bucket = dest>>8. Binning writes land in per-block contiguous runs; final placement
// scatters only inside a ~32KB bucket window (L1/L2-resident). deg/dnorm/rowptr derived
// per bucket in LDS. pairs value carries ew*dnorm[row].

// ---- bucket histogram (block-local LDS, then 1 atomic per bucket) ----
__global__ __launch_bounds__(256) void k_bcount(const int* __restrict__ col, int E,
                                                int* __restrict__ bcnt){
  __shared__ int h[512];
  int t=threadIdx.x;
  for(int i=t;i<512;i+=256) h[i]=0;
  __syncthreads();
  int e0=blockIdx.x*4096, e1=min(e0+4096,E);
  for(int e=e0+t;e<e1;e+=256) atomicAdd(&h[((unsigned)col[e])>>8],1);
  __syncthreads();
  for(int i=t;i<512;i+=256) if(h[i]) atomicAdd(&bcnt[i],h[i]);
}

// ---- exclusive scan of bucket counts (single block) ----
__global__ void k_bscan(const int* __restrict__ bcnt, int B, int E,
                        int* __restrict__ bbase, int* __restrict__ cursor){
  __shared__ int s[512];
  int t=threadIdx.x;
  int v=(t<B)?bcnt[t]:0;
  s[t]=v; __syncthreads();
  for(int off=1;off<512;off<<=1){ int u=(t>=off)?s[t-off]:0; __syncthreads(); s[t]+=u; __syncthreads(); }
  if(t<B){ bbase[t]=s[t]-v; cursor[t]=s[t]-v; }
  if(t==0) bbase[B]=E;
}

// ---- binning: stg[...] = (local<<24 | row, ew), grouped by bucket ----
__global__ __launch_bounds__(256) void k_bfill(const int* __restrict__ row, const int* __restrict__ col,
    const float* __restrict__ ew, int E, int* __restrict__ cursor, uint2* __restrict__ stg){
  __shared__ int h[512];
  __shared__ int ofs[512];
  int t=threadIdx.x;
  for(int i=t;i<512;i+=256) h[i]=0;
  __syncthreads();
  int e0=blockIdx.x*4096, e1=min(e0+4096,E);
  for(int e=e0+t;e<e1;e+=256) atomicAdd(&h[((unsigned)col[e])>>8],1);
  __syncthreads();
  for(int i=t;i<512;i+=256) ofs[i] = h[i] ? atomicAdd(&cursor[i],h[i]) : 0;
  __syncthreads();
  for(int i=t;i<512;i+=256) h[i]=0;
  __syncthreads();
  for(int e=e0+t;e<e1;e+=256){
    unsigned d=(unsigned)col[e];
    int b=d>>8;
    int lp=atomicAdd(&h[b],1);
    stg[ofs[b]+lp]=make_uint2(((d&255u)<<24)|(unsigned)row[e], __float_as_uint(ew[e]));
  }
}

// ---- per-bucket: degree -> dnorm + rowptr (LDS count + scan) ----
__global__ __launch_bounds__(256) void k_p2a(const uint2* __restrict__ stg, const int* __restrict__ bbase,
    int N, int E, float* __restrict__ dnorm, int* __restrict__ rowptr){
  __shared__ int cnt[256];
  __shared__ int pre[256];
  int b=blockIdx.x, t=threadIdx.x;
  cnt[t]=0; __syncthreads();
  int s0=bbase[b], s1=bbase[b+1];
  for(int p=s0+t;p<s1;p+=256) atomicAdd(&cnt[stg[p].x>>24],1);
  __syncthreads();
  int v=cnt[t];
  pre[t]=v; __syncthreads();
  for(int off=1;off<256;off<<=1){ int u=(t>=off)?pre[t-off]:0; __syncthreads(); pre[t]+=u; __syncthreads(); }
  int node=(b<<8)+t;
  if(node<N){
    dnorm[node]= v>0 ? rsqrtf((float)v) : 0.f;   // nan_to_num: deg==0 -> coefficient 0
    rowptr[node]=s0+pre[t]-v;
    if(node==N-1) rowptr[N]=E;
  }
}

// ---- per-bucket: place records -> pairs, folding dnorm[row] into the value ----
__global__ __launch_bounds__(256) void k_p2b(const uint2* __restrict__ stg, const int* __restrict__ bbase,
    int N, const int* __restrict__ rowptr, const float* __restrict__ dnorm,
    float2* __restrict__ pairs){
  __shared__ int cur[256];
  int b=blockIdx.x, t=threadIdx.x;
  int node=(b<<8)+t;
  cur[t]=(node<N)?rowptr[node]:0;
  __syncthreads();
  int s0=bbase[b], s1=bbase[b+1];
  for(int p=s0+t;p<s1;p+=256){
    uint2 rec=stg[p];
    int r=(int)(rec.x&0xFFFFFFu);
    int pos=atomicAdd(&cur[rec.x>>24],1);
    pairs[pos]=make_float2(__int_as_float(r), __uint_as_float(rec.y)*dnorm[r]);
  }
}

// ---------------- SpMM bf16 v11b: wave/dest, 2 cols/lane, masked-full-batch tail ----------------
// Body = proven v8 structure: pairs loads are wave-uniform -> SGPR (s_load); gather
// address = SGPR base + fixed lane offset (saddr form); weight is an SGPR fma operand.
// Scalar pipe does ALL edge bookkeeping for free (v10 lesson: any per-lane edge
// addressing doubles VALU time). Tail loops (serialized latency rounds, low MLP)
// replaced by ONE masked full 16-batch clamped to p0=max(0,end-16). Mask is TWO-sided
// (v11 bug: when end<16, p0 clamps to 0 and the window runs past end into the next
// node's records): w = (p0+j>=p && p0+j<end) ? val : 0, all scalar cmps. Rows in
// masked slots stay valid & cache-hot. Every wave = ceil(deg/16) full-MLP rounds.
// BN0 applies stage-0 BN+ReLU inline to each gathered value (gather source = raw z0).
template<bool BN0>
__global__ __launch_bounds__(256) void k_spmm_bf(const float2* __restrict__ pairs,
    const int* __restrict__ rowptr, const float* __restrict__ dnorm,
    const unsigned short* __restrict__ hb, unsigned short* __restrict__ zb, int N,
    const float* __restrict__ bnst, const float* __restrict__ gamma,
    const float* __restrict__ beta, float invN){
  int wid=(blockIdx.x*256+threadIdx.x)>>6;
  int lane=threadIdx.x&63;
  if(wid>=N) return;
  float sc0=0.f,sh0=0.f,sc1=0.f,sh1=0.f;
  if(BN0){
    int c0=lane<<1;
    float m0=bnst[c0]*invN,      m1=bnst[c0+1]*invN;
    float v0=bnst[128+c0]*invN-m0*m0, v1=bnst[129+c0]*invN-m1*m1;
    sc0=rsqrtf(v0+EPS)*gamma[c0];   sh0=beta[c0]-m0*sc0;
    sc1=rsqrtf(v1+EPS)*gamma[c0+1]; sh1=beta[c0+1]-m1*sc1;
  }
  int beg=__builtin_amdgcn_readfirstlane(rowptr[wid]);
  int end=__builtin_amdgcn_readfirstlane(rowptr[wid+1]);
  float ax=0.f, ay=0.f;
  int p=beg;
  // -------- full batches: 16 scalar pair-loads, 16 gathers in flight --------
  for(; p+16<=end; p+=16){
    float2 pr[16]; unsigned int u[16];
    #pragma unroll
    for(int j=0;j<16;j++) pr[j]=pairs[p+j];
    #pragma unroll
    for(int j=0;j<16;j++)
      u[j]=*(const unsigned int*)(hb + (((size_t)__float_as_int(pr[j].x))<<7) + (lane<<1));
    #pragma unroll
    for(int j=0;j<16;j++){
      float f0=bflo(u[j]), f1=bfhi(u[j]);
      if(BN0){ f0=fmaxf(fmaf(f0,sc0,sh0),0.f); f1=fmaxf(fmaf(f1,sc1,sh1),0.f); }
      ax=fmaf(pr[j].y,f0,ax); ay=fmaf(pr[j].y,f1,ay);
    }
  }
  // -------- remainder: ONE masked full batch at p0=max(0,end-16) --------
  // Two-sided scalar mask: slot live iff p <= p0+j < end. Dead slots keep a valid,
  // cache-hot row; weight -> 0 via s_cselect. Full 16-gather MLP, no serial tail.
  if(p<end){
    int p0=max(0,end-16);
    float2 pr[16]; unsigned int u[16];
    #pragma unroll
    for(int j=0;j<16;j++) pr[j]=pairs[p0+j];
    #pragma unroll
    for(int j=0;j<16;j++)
      u[j]=*(const unsigned int*)(hb + (((size_t)__float_as_int(pr[j].x))<<7) + (lane<<1));
    #pragma unroll
    for(int j=0;j<16;j++){
      float w = (p0+j>=p && p0+j<end) ? pr[j].y : 0.f;   // scalar cmps + cselect
      float f0=bflo(u[j]), f1=bfhi(u[j]);
      if(BN0){ f0=fmaxf(fmaf(f0,sc0,sh0),0.f); f1=fmaxf(fmaf(f1,sc1,sh1),0.f); }
      ax=fmaf(w,f0,ax); ay=fmaf(w,f1,ay);
    }
  }
  float dn=dnorm[wid];
  *(unsigned int*)(zb + ((size_t)wid<<7) + (lane<<1)) = pack_bf16(ax*dn, ay*dn);
}

// ---------------- MFMA GEMM (N x 128 @ 128 x 128) + fused BN sum/sumsq ----------------
// bf16 MFMA 16x16x32. Wave = 64 rows x 128 cols (4 row-tiles x 8 ntiles, K = 4x32).
// W staged once/block into LDS transposed bf16 (pitch 136). A-frags straight from
// global (16B/lane). In-place safe. Layouts: A m=lane&15,k=quad*8+j; C/D col=lane&15,
// row=quad*4+reg [m89/m120-verified].
template<bool F32A>
__global__ __launch_bounds__(256,2) void k_gemm_bn(const void* __restrict__ Ap,
    const float* __restrict__ W, const float* __restrict__ bias,
    unsigned short* __restrict__ Zb, float* __restrict__ stats, int N){
  __shared__ __align__(16) unsigned short sWT[128*136];   // 34816 B
  int t=threadIdx.x;

  for(int it=t; it<4096; it+=256){
    float4 v=((const float4*)W)[it];
    int lin=it*4; int k=lin>>7; int c0=lin&127;
    sWT[(c0+0)*136+k]=f2bf(v.x);
    sWT[(c0+1)*136+k]=f2bf(v.y);
    sWT[(c0+2)*136+k]=f2bf(v.z);
    sWT[(c0+3)*136+k]=f2bf(v.w);
  }
  __syncthreads();

  int w=t>>6, lane=t&63, n=lane&15, quad=lane>>4;
  int r0w = blockIdx.x*256 + w*64;

  f32x4 acc[8][4];
  #pragma unroll
  for(int nt=0;nt<8;nt++)
    #pragma unroll
    for(int rt=0;rt<4;rt++){ f32x4 z4={0.f,0.f,0.f,0.f}; acc[nt][rt]=z4; }

  #pragma unroll
  for(int ks=0; ks<4; ks++){
    int k0 = ks*32 + quad*8;
    bf16x8 a[4];
    #pragma unroll
    for(int rt=0;rt<4;rt++){
      int r = r0w + rt*16 + n;
      bf16x8 af={0,0,0,0,0,0,0,0};
      if(r<N){
        if(F32A){
          const float* Af=(const float*)Ap;
          float4 u0=*(const float4*)&Af[(size_t)r*128 + k0];
          float4 u1=*(const float4*)&Af[(size_t)r*128 + k0 + 4];
          af[0]=(short)f2bf(u0.x); af[1]=(short)f2bf(u0.y);
          af[2]=(short)f2bf(u0.z); af[3]=(short)f2bf(u0.w);
          af[4]=(short)f2bf(u1.x); af[5]=(short)f2bf(u1.y);
          af[6]=(short)f2bf(u1.z); af[7]=(short)f2bf(u1.w);
        }else{
          af = *(const bf16x8*)((const unsigned short*)Ap + (size_t)r*128 + k0);
        }
      }
      a[rt]=af;
    }
    #pragma unroll
    for(int nt=0;nt<8;nt++){
      bf16x8 b = *(const bf16x8*)&sWT[(nt*16+n)*136 + k0];
      #pragma unroll
      for(int rt=0;rt<4;rt++)
        acc[nt][rt]=__builtin_amdgcn_mfma_f32_16x16x32_bf16(a[rt], b, acc[nt][rt], 0,0,0);
    }
  }

  __syncthreads();                        // reuse sWT for stats partials
  float* sS=(float*)sWT;                  // [16][132]
  float* sQ=sS + 16*132;                  // [16][132]
  #pragma unroll
  for(int nt=0;nt<8;nt++){
    int c=nt*16+n;
    float bc=bias[c];
    float s=0.f,q=0.f;
    #pragma unroll
    for(int rt=0;rt<4;rt++){
      #pragma unroll
      for(int i=0;i<4;i++){
        int r=r0w + rt*16 + quad*4 + i;
        if(r<N){
          float z=acc[nt][rt][i]+bc;
          Zb[(size_t)r*128+c]=f2bf(z);
          s+=z; q+=z*z;
        }
      }
    }
    sS[(w*4+quad)*132+c]=s;
    sQ[(w*4+quad)*132+c]=q;
  }
  __syncthreads();
  if(t<128){
    float s=0.f,q=0.f;
    #pragma unroll
    for(int g=0;g<16;g++){ s+=sS[g*132+t]; q+=sQ[g*132+t]; }
    atomicAdd(&stats[t],s); atomicAdd(&stats[128+t],q);
  }
}

// ---------------- apply: BN finalize (in-block) + scale/shift + ReLU + residual ----------------
// BNRES: residual operand is raw z0 -> apply stage-0 BN+ReLU inline (h0 never
// materialized). smi[0:256)=this stage scale/shift, smi[256:512)=residual stage's.
template<bool OUTF32, bool BNRES>
__global__ __launch_bounds__(256) void k_apply(const unsigned short* __restrict__ Zb,
    const float* __restrict__ stats, const float* __restrict__ gamma,
    const float* __restrict__ beta, float invN,
    const unsigned short* __restrict__ res,
    const float* __restrict__ rstats, const float* __restrict__ rgamma,
    const float* __restrict__ rbeta,
    float* __restrict__ outf, unsigned short* __restrict__ outb, int n4){
  __shared__ float smi[512];
  int t=threadIdx.x;
  if(t<128){
    float mean=stats[t]*invN;
    float var=stats[128+t]*invN - mean*mean;
    float sc=rsqrtf(var+EPS)*gamma[t];
    smi[t]=sc; smi[128+t]=beta[t]-mean*sc;
    if(BNRES){
      float rm=rstats[t]*invN;
      float rv=rstats[128+t]*invN - rm*rm;
      float rs=rsqrtf(rv+EPS)*rgamma[t];
      smi[256+t]=rs; smi[384+t]=rbeta[t]-rm*rs;
    }
  }
  __syncthreads();
  int i=blockIdx.x*256+t;
  if(i>=n4) return;
  int c=(i&31)*4;
  uint2 zu=((const uint2*)Zb)[i];
  float4 z;
  z.x=bflo(zu.x); z.y=bfhi(zu.x);
  z.z=bflo(zu.y); z.w=bfhi(zu.y);
  float4 sc=*(const float4*)&smi[c];
  float4 sh=*(const float4*)&smi[128+c];
  float4 o;
  o.x=fmaxf(fmaf(z.x,sc.x,sh.x),0.f);
  o.y=fmaxf(fmaf(z.y,sc.y,sh.y),0.f);
  o.z=fmaxf(fmaf(z.z,sc.z,sh.z),0.f);
  o.w=fmaxf(fmaf(z.w,sc.w,sh.w),0.f);
  if(res){
    uint2 ru=((const uint2*)res)[i];
    float4 r;
    r.x=bflo(ru.x); r.y=bfhi(ru.x);
    r.z=bflo(ru.y); r.w=bfhi(ru.y);
    if(BNRES){
      float4 rs=*(const float4*)&smi[256+c];
      float4 rh=*(const float4*)&smi[384+c];
      r.x=fmaxf(fmaf(r.x,rs.x,rh.x),0.f);
      r.y=fmaxf(fmaf(r.y,rs.y,rh.y),0.f);
      r.z=fmaxf(fmaf(r.z,rs.z,rh.z),0.f);
      r.w=fmaxf(fmaf(r.w,rs.w,rh.w),0.f);
    }
    o.x+=r.x; o.y+=r.y; o.z+=r.z; o.w+=r.w;
  }
  if(OUTF32){
    ((float4*)outf)[i]=o;
  }else{
    uint2 pk; pk.x=pack_bf16(o.x,o.y); pk.y=pack_bf16(o.z,o.w);
    ((uint2*)outb)[i]=pk;
  }
}

extern "C" void kernel_launch(void* const* d_in, const int* in_sizes, int n_in,
                              void* d_out, int out_size, void* d_ws, size_t ws_size,
                              hipStream_t stream){
  const float* x      = (const float*)d_in[0];
  const int*   ei     = (const int*)  d_in[1];
  const float* ew     = (const float*)d_in[2];
  const float* fc_w   = (const float*)d_in[3];
  const float* fc_b   = (const float*)d_in[4];
  const float* conv_w = (const float*)d_in[5];
  const float* conv_b = (const float*)d_in[6];
  const float* gamma  = (const float*)d_in[7];
  const float* beta   = (const float*)d_in[8];
  float* out = (float*)d_out;

  int N = in_sizes[0]/H;
  int E = in_sizes[2];
  const int* row = ei;
  const int* col = ei + E;
  int B = (N+NPB-1)/NPB;                 // buckets

  // workspace layout (~78 MB)
  size_t NH = (size_t)N*H;
  unsigned short* zb   = (unsigned short*)d_ws;  // N*H bf16: z0, then h1
  unsigned short* hbuf = zb + NH;                // N*H bf16: agg / z1 / z2
  uint2*  stg    = (uint2*)(hbuf + NH);          // E bucket-grouped records
  float2* pairs  = (float2*)(stg + E);           // E final CSR records (val = ew*dnorm[row])
  float*  stats  = (float*)(pairs + E);          // 3*256   } contiguous for
  int*    bcnt   = (int*)(stats + 768);          // 512     } single memset
  int*    bbase  = bcnt + 512;                   // 513
  int*    cursor = bbase + 513;                  // 512
  float*  dnorm  = (float*)(cursor + 512);       // N
  int*    rowptr = (int*)(dnorm + N);            // N+1

  hipMemsetAsync(stats, 0, sizeof(float)*(768+512), stream);

  int gE4k = (E+4095)/4096;
  k_bcount<<<gE4k,256,0,stream>>>(col,E,bcnt);
  k_bscan<<<1,512,0,stream>>>(bcnt,B,E,bbase,cursor);
  k_bfill<<<gE4k,256,0,stream>>>(row,col,ew,E,cursor,stg);
  k_p2a<<<B,256,0,stream>>>(stg,bbase,N,E,dnorm,rowptr);
  k_p2b<<<B,256,0,stream>>>(stg,bbase,N,rowptr,dnorm,pairs);

  int GB=(N+255)/256;
  int gApply=((N*32)+255)/256;
  int gSpmm=(N+3)/4;
  float invN=1.f/(float)N;

  // stage 0: z0 = x @ fc_w + fc_b  -> zb (h0 = relu(bn0(z0)) is NEVER materialized)
  k_gemm_bn<true><<<GB,256,0,stream>>>(x, fc_w, fc_b, zb, stats, N);

  // layer 0: agg = A_hat @ relu(bn0(z0))  [BN0 inline in gather]  -> hbuf
  k_spmm_bf<true><<<gSpmm,256,0,stream>>>(pairs,rowptr,dnorm, zb, hbuf, N,
                                          stats, gamma, beta, invN);
  k_gemm_bn<false><<<GB,256,0,stream>>>(hbuf, conv_w, conv_b, hbuf, stats+256, N);
  // h1 = relu(bn1(z1)) + relu(bn0(z0))  -> zb (in-place over z0)
  k_apply<false,true><<<gApply,256,0,stream>>>(hbuf, stats+256, gamma+H, beta+H, invN,
                                               zb, stats, gamma, beta,
                                               nullptr, zb, N*32);

  // layer 1: out = relu(bn2(agg(h1) @ W1 + b1)) + h1 -> fp32 d_out
  k_spmm_bf<false><<<gSpmm,256,0,stream>>>(pairs,rowptr,dnorm, zb, hbuf, N,
                                           nullptr, nullptr, nullptr, 0.f);
  k_gemm_bn<false><<<GB,256,0,stream>>>(hbuf, conv_w + (size_t)H*H, conv_b + H, hbuf, stats+512, N);
  k_apply<true,false><<<gApply,256,0,stream>>>(hbuf, stats+512, gamma+2*H, beta+2*H, invN,
                                               zb, nullptr, nullptr, nullptr,
                                               out, nullptr, N*32);
}

// Round 4
// 449.844 us; speedup vs baseline: 1.0447x; 1.0360x over previous
//
#include <hip/hip_runtime.h>

#define H 128
#define EPS 1e-5f
#define NPB 256      // nodes per bucket (pow2); bucket = node >> 8

typedef __attribute__((ext_vector_type(8))) short bf16x8;
typedef __attribute__((ext_vector_type(4))) float f32x4;

__device__ inline unsigned short f2bf(float f){
  unsigned int u=__float_as_uint(f);
  return (unsigned short)((u + 0x7FFFu + ((u>>16)&1u))>>16);
}
__device__ inline unsigned int pack_bf16(float a, float b){
  unsigned int ua=__float_as_uint(a), ub=__float_as_uint(b);
  ua = (ua + 0x7FFFu + ((ua>>16)&1u)) >> 16;
  ub = (ub + 0x7FFFu + ((ub>>16)&1u)) & 0xFFFF0000u;
  return ua | ub;
}
__device__ inline float bflo(unsigned int u){ return __uint_as_float(u<<16); }
__device__ inline float bfhi(unsigned int u){ return __uint_as_float(u&0xFFFF0000u); }

// ============ CSR build via 2-level bucket sort ============
// Bucket = dest>>8. Binning writes land in per-block contiguous runs; final placement
// scatters only inside a ~32KB bucket window (L1/L2-resident). deg/dnorm/rowptr derived
// per bucket in LDS. pairs value carries ew*dnorm[row].

// ---- bucket histogram (block-local LDS, then 1 atomic per bucket) ----
__global__ __launch_bounds__(256) void k_bcount(const int* __restrict__ col, int E,
                                                int* __restrict__ bcnt){
  __shared__ int h[512];
  int t=threadIdx.x;
  for(int i=t;i<512;i+=256) h[i]=0;
  __syncthreads();
  int e0=blockIdx.x*4096, e1=min(e0+4096,E);
  for(int e=e0+t;e<e1;e+=256) atomicAdd(&h[((unsigned)col[e])>>8],1);
  __syncthreads();
  for(int i=t;i<512;i+=256) if(h[i]) atomicAdd(&bcnt[i],h[i]);
}

// ---- exclusive scan of bucket counts (single block) ----
__global__ void k_bscan(const int* __restrict__ bcnt, int B, int E,
                        int* __restrict__ bbase, int* __restrict__ cursor){
  __shared__ int s[512];
  int t=threadIdx.x;
  int v=(t<B)?bcnt[t]:0;
  s[t]=v; __syncthreads();
  for(int off=1;off<512;off<<=1){ int u=(t>=off)?s[t-off]:0; __syncthreads(); s[t]+=u; __syncthreads(); }
  if(t<B){ bbase[t]=s[t]-v; cursor[t]=s[t]-v; }
  if(t==0) bbase[B]=E;
}

// ---- binning: stg[...] = (local<<24 | row, ew), grouped by bucket ----
__global__ __launch_bounds__(256) void k_bfill(const int* __restrict__ row, const int* __restrict__ col,
    const float* __restrict__ ew, int E, int* __restrict__ cursor, uint2* __restrict__ stg){
  __shared__ int h[512];
  __shared__ int ofs[512];
  int t=threadIdx.x;
  for(int i=t;i<512;i+=256) h[i]=0;
  __syncthreads();
  int e0=blockIdx.x*4096, e1=min(e0+4096,E);
  for(int e=e0+t;e<e1;e+=256) atomicAdd(&h[((unsigned)col[e])>>8],1);
  __syncthreads();
  for(int i=t;i<512;i+=256) ofs[i] = h[i] ? atomicAdd(&cursor[i],h[i]) : 0;
  __syncthreads();
  for(int i=t;i<512;i+=256) h[i]=0;
  __syncthreads();
  for(int e=e0+t;e<e1;e+=256){
    unsigned d=(unsigned)col[e];
    int b=d>>8;
    int lp=atomicAdd(&h[b],1);
    stg[ofs[b]+lp]=make_uint2(((d&255u)<<24)|(unsigned)row[e], __float_as_uint(ew[e]));
  }
}

// ---- per-bucket: degree -> dnorm + rowptr (LDS count + scan) ----
__global__ __launch_bounds__(256) void k_p2a(const uint2* __restrict__ stg, const int* __restrict__ bbase,
    int N, int E, float* __restrict__ dnorm, int* __restrict__ rowptr){
  __shared__ int cnt[256];
  __shared__ int pre[256];
  int b=blockIdx.x, t=threadIdx.x;
  cnt[t]=0; __syncthreads();
  int s0=bbase[b], s1=bbase[b+1];
  for(int p=s0+t;p<s1;p+=256) atomicAdd(&cnt[stg[p].x>>24],1);
  __syncthreads();
  int v=cnt[t];
  pre[t]=v; __syncthreads();
  for(int off=1;off<256;off<<=1){ int u=(t>=off)?pre[t-off]:0; __syncthreads(); pre[t]+=u; __syncthreads(); }
  int node=(b<<8)+t;
  if(node<N){
    dnorm[node]= v>0 ? rsqrtf((float)v) : 0.f;   // nan_to_num: deg==0 -> coefficient 0
    rowptr[node]=s0+pre[t]-v;
    if(node==N-1) rowptr[N]=E;
  }
}

// ---- per-bucket: place records -> pairs, folding dnorm[row] into the value ----
__global__ __launch_bounds__(256) void k_p2b(const uint2* __restrict__ stg, const int* __restrict__ bbase,
    int N, const int* __restrict__ rowptr, const float* __restrict__ dnorm,
    float2* __restrict__ pairs){
  __shared__ int cur[256];
  int b=blockIdx.x, t=threadIdx.x;
  int node=(b<<8)+t;
  cur[t]=(node<N)?rowptr[node]:0;
  __syncthreads();
  int s0=bbase[b], s1=bbase[b+1];
  for(int p=s0+t;p<s1;p+=256){
    uint2 rec=stg[p];
    int r=(int)(rec.x&0xFFFFFFu);
    int pos=atomicAdd(&cur[rec.x>>24],1);
    pairs[pos]=make_float2(__int_as_float(r), __uint_as_float(rec.y)*dnorm[r]);
  }
}

// ---- one-time W transpose+convert: Wt[m][c*136+k] = bf16(W_m[k][c]) ----
// m=0: fc_w; m=1,2: conv_w[0],conv_w[1]. Coalesced reads; tiny one-shot kernel.
__global__ __launch_bounds__(256) void k_wconv(const float* __restrict__ W0,
    const float* __restrict__ W1, unsigned short* __restrict__ Wt){
  int m=blockIdx.x>>6;
  int lin=((blockIdx.x&63)<<8)+threadIdx.x;     // 0..16383
  const float* src = (m==0) ? W0 : (W1 + (size_t)(m-1)*16384);
  int k=lin>>7, c=lin&127;
  Wt[(size_t)m*17408 + c*136 + k] = f2bf(src[lin]);
}

// ---------------- SpMM bf16: wave/dest, 2 cols/lane, 16 gathers in flight ----------------
// Proven v8 body (61us, best of 4 attempts). Edge bookkeeping is fully scalar: pairs
// loads are wave-uniform s_load; gather = SGPR base + fixed lane offset; weight is an
// SGPR fma operand. v10 lesson: per-lane edge addressing doubles VALU time. v11 lesson:
// masked-full-batch tail adds ~50% edge work (avg deg 16) and loses more than the
// removed serialization gains. Keep 16/4/1 tails.
// BN0 applies stage-0 BN+ReLU inline to each gathered value (gather source = raw z0).
template<bool BN0>
__global__ __launch_bounds__(256) void k_spmm_bf(const float2* __restrict__ pairs,
    const int* __restrict__ rowptr, const float* __restrict__ dnorm,
    const unsigned short* __restrict__ hb, unsigned short* __restrict__ zb, int N,
    const float* __restrict__ bnst, const float* __restrict__ gamma,
    const float* __restrict__ beta, float invN){
  int wid=(blockIdx.x*256+threadIdx.x)>>6;
  int lane=threadIdx.x&63;
  if(wid>=N) return;
  float sc0=0.f,sh0=0.f,sc1=0.f,sh1=0.f;
  if(BN0){
    int c0=lane<<1;
    float m0=bnst[c0]*invN,      m1=bnst[c0+1]*invN;
    float v0=bnst[128+c0]*invN-m0*m0, v1=bnst[129+c0]*invN-m1*m1;
    sc0=rsqrtf(v0+EPS)*gamma[c0];   sh0=beta[c0]-m0*sc0;
    sc1=rsqrtf(v1+EPS)*gamma[c0+1]; sh1=beta[c0+1]-m1*sc1;
  }
  int beg=__builtin_amdgcn_readfirstlane(rowptr[wid]);
  int end=__builtin_amdgcn_readfirstlane(rowptr[wid+1]);
  float ax=0.f, ay=0.f;
  int p=beg;
  for(; p+16<=end; p+=16){
    float2 pr[16]; unsigned int u[16];
    #pragma unroll
    for(int j=0;j<16;j++) pr[j]=pairs[p+j];
    #pragma unroll
    for(int j=0;j<16;j++)
      u[j]=*(const unsigned int*)(hb + (((size_t)__float_as_int(pr[j].x))<<7) + (lane<<1));
    #pragma unroll
    for(int j=0;j<16;j++){
      float f0=bflo(u[j]), f1=bfhi(u[j]);
      if(BN0){ f0=fmaxf(fmaf(f0,sc0,sh0),0.f); f1=fmaxf(fmaf(f1,sc1,sh1),0.f); }
      ax=fmaf(pr[j].y,f0,ax); ay=fmaf(pr[j].y,f1,ay);
    }
  }
  for(; p+4<=end; p+=4){
    float2 pr[4]; unsigned int u[4];
    #pragma unroll
    for(int j=0;j<4;j++) pr[j]=pairs[p+j];
    #pragma unroll
    for(int j=0;j<4;j++)
      u[j]=*(const unsigned int*)(hb + (((size_t)__float_as_int(pr[j].x))<<7) + (lane<<1));
    #pragma unroll
    for(int j=0;j<4;j++){
      float f0=bflo(u[j]), f1=bfhi(u[j]);
      if(BN0){ f0=fmaxf(fmaf(f0,sc0,sh0),0.f); f1=fmaxf(fmaf(f1,sc1,sh1),0.f); }
      ax=fmaf(pr[j].y,f0,ax); ay=fmaf(pr[j].y,f1,ay);
    }
  }
  for(; p<end; ++p){
    float2 pr=pairs[p];
    unsigned int u=*(const unsigned int*)(hb + (((size_t)__float_as_int(pr.x))<<7) + (lane<<1));
    float f0=bflo(u), f1=bfhi(u);
    if(BN0){ f0=fmaxf(fmaf(f0,sc0,sh0),0.f); f1=fmaxf(fmaf(f1,sc1,sh1),0.f); }
    ax=fmaf(pr.y,f0,ax); ay=fmaf(pr.y,f1,ay);
  }
  float dn=dnorm[wid];
  *(unsigned int*)(zb + ((size_t)wid<<7) + (lane<<1)) = pack_bf16(ax*dn, ay*dn);
}

// ---------------- MFMA GEMM (N x 128 @ 128 x 128) + fused BN sum/sumsq ----------------
// v2: 128 rows/block (grid ~782 = 3.05 blocks/CU, balanced; was 391 @ 2/CU cap = 76%
// efficiency + only 8 waves/CU). W pre-transposed bf16 in global (k_wconv) -> staging
// is a pure 16B-vector copy, no per-block f2bf/scalar ds_writes. acc halves to 8x2
// f32x4 -> fits __launch_bounds__(256,3) (12 waves/CU). In-place safe: each block
// reads exactly the rows it writes. Layouts: A m=lane&15,k=quad*8+j; C/D col=lane&15,
// row=quad*4+reg [m89/m120-verified].
template<bool F32A>
__global__ __launch_bounds__(256,3) void k_gemm_bn(const void* __restrict__ Ap,
    const unsigned short* __restrict__ Wt, const float* __restrict__ bias,
    unsigned short* __restrict__ Zb, float* __restrict__ stats, int N){
  __shared__ __align__(16) unsigned short sWT[128*136];   // 34816 B
  int t=threadIdx.x;

  {
    const uint4* gw=(const uint4*)Wt;                     // 2176 x 16B
    uint4* sw=(uint4*)sWT;
    #pragma unroll
    for(int it=0; it<8; it++) sw[t + it*256] = gw[t + it*256];
    if(t<128) sw[2048+t]=gw[2048+t];
  }
  __syncthreads();

  int w=t>>6, lane=t&63, n=lane&15, quad=lane>>4;
  int r0w = blockIdx.x*128 + w*32;

  f32x4 acc[8][2];
  #pragma unroll
  for(int nt=0;nt<8;nt++)
    #pragma unroll
    for(int rt=0;rt<2;rt++){ f32x4 z4={0.f,0.f,0.f,0.f}; acc[nt][rt]=z4; }

  #pragma unroll
  for(int ks=0; ks<4; ks++){
    int k0 = ks*32 + quad*8;
    bf16x8 a[2];
    #pragma unroll
    for(int rt=0;rt<2;rt++){
      int r = r0w + rt*16 + n;
      bf16x8 af={0,0,0,0,0,0,0,0};
      if(r<N){
        if(F32A){
          const float* Af=(const float*)Ap;
          float4 u0=*(const float4*)&Af[(size_t)r*128 + k0];
          float4 u1=*(const float4*)&Af[(size_t)r*128 + k0 + 4];
          af[0]=(short)f2bf(u0.x); af[1]=(short)f2bf(u0.y);
          af[2]=(short)f2bf(u0.z); af[3]=(short)f2bf(u0.w);
          af[4]=(short)f2bf(u1.x); af[5]=(short)f2bf(u1.y);
          af[6]=(short)f2bf(u1.z); af[7]=(short)f2bf(u1.w);
        }else{
          af = *(const bf16x8*)((const unsigned short*)Ap + (size_t)r*128 + k0);
        }
      }
      a[rt]=af;
    }
    #pragma unroll
    for(int nt=0;nt<8;nt++){
      bf16x8 b = *(const bf16x8*)&sWT[(nt*16+n)*136 + k0];
      #pragma unroll
      for(int rt=0;rt<2;rt++)
        acc[nt][rt]=__builtin_amdgcn_mfma_f32_16x16x32_bf16(a[rt], b, acc[nt][rt], 0,0,0);
    }
  }

  __syncthreads();                        // reuse sWT for stats partials
  float* sS=(float*)sWT;                  // [16][132]
  float* sQ=sS + 16*132;                  // [16][132]
  #pragma unroll
  for(int nt=0;nt<8;nt++){
    int c=nt*16+n;
    float bc=bias[c];
    float s=0.f,q=0.f;
    #pragma unroll
    for(int rt=0;rt<2;rt++){
      #pragma unroll
      for(int i=0;i<4;i++){
        int r=r0w + rt*16 + quad*4 + i;
        if(r<N){
          float z=acc[nt][rt][i]+bc;
          Zb[(size_t)r*128+c]=f2bf(z);
          s+=z; q+=z*z;
        }
      }
    }
    sS[(w*4+quad)*132+c]=s;
    sQ[(w*4+quad)*132+c]=q;
  }
  __syncthreads();
  if(t<128){
    float s=0.f,q=0.f;
    #pragma unroll
    for(int g=0;g<16;g++){ s+=sS[g*132+t]; q+=sQ[g*132+t]; }
    atomicAdd(&stats[t],s); atomicAdd(&stats[128+t],q);
  }
}

// ---------------- apply: BN finalize (in-block) + scale/shift + ReLU + residual ----------------
// BNRES: residual operand is raw z0 -> apply stage-0 BN+ReLU inline (h0 never
// materialized). smi[0:256)=this stage scale/shift, smi[256:512)=residual stage's.
template<bool OUTF32, bool BNRES>
__global__ __launch_bounds__(256) void k_apply(const unsigned short* __restrict__ Zb,
    const float* __restrict__ stats, const float* __restrict__ gamma,
    const float* __restrict__ beta, float invN,
    const unsigned short* __restrict__ res,
    const float* __restrict__ rstats, const float* __restrict__ rgamma,
    const float* __restrict__ rbeta,
    float* __restrict__ outf, unsigned short* __restrict__ outb, int n4){
  __shared__ float smi[512];
  int t=threadIdx.x;
  if(t<128){
    float mean=stats[t]*invN;
    float var=stats[128+t]*invN - mean*mean;
    float sc=rsqrtf(var+EPS)*gamma[t];
    smi[t]=sc; smi[128+t]=beta[t]-mean*sc;
    if(BNRES){
      float rm=rstats[t]*invN;
      float rv=rstats[128+t]*invN - rm*rm;
      float rs=rsqrtf(rv+EPS)*rgamma[t];
      smi[256+t]=rs; smi[384+t]=rbeta[t]-rm*rs;
    }
  }
  __syncthreads();
  int i=blockIdx.x*256+t;
  if(i>=n4) return;
  int c=(i&31)*4;
  uint2 zu=((const uint2*)Zb)[i];
  float4 z;
  z.x=bflo(zu.x); z.y=bfhi(zu.x);
  z.z=bflo(zu.y); z.w=bfhi(zu.y);
  float4 sc=*(const float4*)&smi[c];
  float4 sh=*(const float4*)&smi[128+c];
  float4 o;
  o.x=fmaxf(fmaf(z.x,sc.x,sh.x),0.f);
  o.y=fmaxf(fmaf(z.y,sc.y,sh.y),0.f);
  o.z=fmaxf(fmaf(z.z,sc.z,sh.z),0.f);
  o.w=fmaxf(fmaf(z.w,sc.w,sh.w),0.f);
  if(res){
    uint2 ru=((const uint2*)res)[i];
    float4 r;
    r.x=bflo(ru.x); r.y=bfhi(ru.x);
    r.z=bflo(ru.y); r.w=bfhi(ru.y);
    if(BNRES){
      float4 rs=*(const float4*)&smi[256+c];
      float4 rh=*(const float4*)&smi[384+c];
      r.x=fmaxf(fmaf(r.x,rs.x,rh.x),0.f);
      r.y=fmaxf(fmaf(r.y,rs.y,rh.y),0.f);
      r.z=fmaxf(fmaf(r.z,rs.z,rh.z),0.f);
      r.w=fmaxf(fmaf(r.w,rs.w,rh.w),0.f);
    }
    o.x+=r.x; o.y+=r.y; o.z+=r.z; o.w+=r.w;
  }
  if(OUTF32){
    ((float4*)outf)[i]=o;
  }else{
    uint2 pk; pk.x=pack_bf16(o.x,o.y); pk.y=pack_bf16(o.z,o.w);
    ((uint2*)outb)[i]=pk;
  }
}

extern "C" void kernel_launch(void* const* d_in, const int* in_sizes, int n_in,
                              void* d_out, int out_size, void* d_ws, size_t ws_size,
                              hipStream_t stream){
  const float* x      = (const float*)d_in[0];
  const int*   ei     = (const int*)  d_in[1];
  const float* ew     = (const float*)d_in[2];
  const float* fc_w   = (const float*)d_in[3];
  const float* fc_b   = (const float*)d_in[4];
  const float* conv_w = (const float*)d_in[5];
  const float* conv_b = (const float*)d_in[6];
  const float* gamma  = (const float*)d_in[7];
  const float* beta   = (const float*)d_in[8];
  float* out = (float*)d_out;

  int N = in_sizes[0]/H;
  int E = in_sizes[2];
  const int* row = ei;
  const int* col = ei + E;
  int B = (N+NPB-1)/NPB;                 // buckets

  // workspace layout (~78 MB)
  size_t NH = (size_t)N*H;
  unsigned short* Wt   = (unsigned short*)d_ws;  // 3*17408 bf16 (pitch-136 WT), 104448 B
  unsigned short* zb   = Wt + 3*17408;           // N*H bf16: z0, then h1
  unsigned short* hbuf = zb + NH;                // N*H bf16: agg / z1 / z2
  uint2*  stg    = (uint2*)(hbuf + NH);          // E bucket-grouped records
  float2* pairs  = (float2*)(stg + E);           // E final CSR records (val = ew*dnorm[row])
  float*  stats  = (float*)(pairs + E);          // 3*256   } contiguous for
  int*    bcnt   = (int*)(stats + 768);          // 512     } single memset
  int*    bbase  = bcnt + 512;                   // 513
  int*    cursor = bbase + 513;                  // 512
  float*  dnorm  = (float*)(cursor + 512);       // N
  int*    rowptr = (int*)(dnorm + N);            // N+1

  hipMemsetAsync(stats, 0, sizeof(float)*(768+512), stream);

  k_wconv<<<192,256,0,stream>>>(fc_w, conv_w, Wt);

  int gE4k = (E+4095)/4096;
  k_bcount<<<gE4k,256,0,stream>>>(col,E,bcnt);
  k_bscan<<<1,512,0,stream>>>(bcnt,B,E,bbase,cursor);
  k_bfill<<<gE4k,256,0,stream>>>(row,col,ew,E,cursor,stg);
  k_p2a<<<B,256,0,stream>>>(stg,bbase,N,E,dnorm,rowptr);
  k_p2b<<<B,256,0,stream>>>(stg,bbase,N,rowptr,dnorm,pairs);

  int GB=(N+127)/128;
  int gApply=((N*32)+255)/256;
  int gSpmm=(N+3)/4;
  float invN=1.f/(float)N;

  // stage 0: z0 = x @ fc_w + fc_b  -> zb (h0 = relu(bn0(z0)) is NEVER materialized)
  k_gemm_bn<true><<<GB,256,0,stream>>>(x, Wt, fc_b, zb, stats, N);

  // layer 0: agg = A_hat @ relu(bn0(z0))  [BN0 inline in gather]  -> hbuf
  k_spmm_bf<true><<<gSpmm,256,0,stream>>>(pairs,rowptr,dnorm, zb, hbuf, N,
                                          stats, gamma, beta, invN);
  k_gemm_bn<false><<<GB,256,0,stream>>>(hbuf, Wt+17408, conv_b, hbuf, stats+256, N);
  // h1 = relu(bn1(z1)) + relu(bn0(z0))  -> zb (in-place over z0)
  k_apply<false,true><<<gApply,256,0,stream>>>(hbuf, stats+256, gamma+H, beta+H, invN,
                                               zb, stats, gamma, beta,
                                               nullptr, zb, N*32);

  // layer 1: out = relu(bn2(agg(h1) @ W1 + b1)) + h1 -> fp32 d_out
  k_spmm_bf<false><<<gSpmm,256,0,stream>>>(pairs,rowptr,dnorm, zb, hbuf, N,
                                           nullptr, nullptr, nullptr, 0.f);
  k_gemm_bn<false><<<GB,256,0,stream>>>(hbuf, Wt+2*17408, conv_b+H, hbuf, stats+512, N);
  k_apply<true,false><<<gApply,256,0,stream>>>(hbuf, stats+512, gamma+2*H, beta+2*H, invN,
                                               zb, nullptr, nullptr, nullptr,
                                               out, nullptr, N*32);
}

// Round 5
// 438.575 us; speedup vs baseline: 1.0716x; 1.0257x over previous
//
#include <hip/hip_runtime.h>

#define H 128
#define EPS 1e-5f
#define NPB 256      // nodes per bucket (pow2); bucket = node >> 8

typedef __attribute__((ext_vector_type(8))) short bf16x8;
typedef __attribute__((ext_vector_type(4))) float f32x4;

__device__ inline unsigned short f2bf(float f){
  unsigned int u=__float_as_uint(f);
  return (unsigned short)((u + 0x7FFFu + ((u>>16)&1u))>>16);
}
__device__ inline unsigned int pack_bf16(float a, float b){
  unsigned int ua=__float_as_uint(a), ub=__float_as_uint(b);
  ua = (ua + 0x7FFFu + ((ua>>16)&1u)) >> 16;
  ub = (ub + 0x7FFFu + ((ub>>16)&1u)) & 0xFFFF0000u;
  return ua | ub;
}
__device__ inline float bflo(unsigned int u){ return __uint_as_float(u<<16); }
__device__ inline float bfhi(unsigned int u){ return __uint_as_float(u&0xFFFF0000u); }

// ============ CSR build via 2-level bucket sort ============
// Bucket = dest>>8. Binning writes land in per-block contiguous runs; final placement
// scatters only inside a ~32KB bucket window (L1/L2-resident). deg/dnorm/rowptr derived
// per bucket in LDS. pairs value carries ew*dnorm[row].
// Round-5: independent kernels are PACKED into one dispatch via blockIdx branch
// (single stream serializes; multi-stream/events banned under graph capture):
//   [wconv | bcount]   and   [gemm1 | bfill]  — disjoint I/O, union LDS.

// ---- bucount body (block-local LDS histogram, then 1 atomic per bucket) ----
__device__ __forceinline__ void bcount_body(const int* __restrict__ col, int E,
                                            int* __restrict__ bcnt, int bid){
  __shared__ int h[512];
  int t=threadIdx.x;
  for(int i=t;i<512;i+=256) h[i]=0;
  __syncthreads();
  int e0=bid*4096, e1=min(e0+4096,E);
  for(int e=e0+t;e<e1;e+=256) atomicAdd(&h[((unsigned)col[e])>>8],1);
  __syncthreads();
  for(int i=t;i<512;i+=256) if(h[i]) atomicAdd(&bcnt[i],h[i]);
}

// ---- one-time W transpose+convert: Wt[m][c*136+k] = bf16(W_m[k][c]) ----
__device__ __forceinline__ void wconv_body(const float* __restrict__ W0,
    const float* __restrict__ W1, unsigned short* __restrict__ Wt, int bid){
  int m=bid>>6;
  int lin=((bid&63)<<8)+threadIdx.x;            // 0..16383
  const float* src = (m==0) ? W0 : (W1 + (size_t)(m-1)*16384);
  int k=lin>>7, c=lin&127;
  Wt[(size_t)m*17408 + c*136 + k] = f2bf(src[lin]);
}

// ---- packed: [wconv (GW blocks) | bcount] ----
__global__ __launch_bounds__(256) void k_wb(const float* __restrict__ W0,
    const float* __restrict__ W1, unsigned short* __restrict__ Wt, int GW,
    const int* __restrict__ col, int E, int* __restrict__ bcnt){
  int bid=blockIdx.x;
  if(bid<GW) wconv_body(W0,W1,Wt,bid);
  else       bcount_body(col,E,bcnt,bid-GW);
}

// ---- exclusive scan of bucket counts (single block) ----
__global__ void k_bscan(const int* __restrict__ bcnt, int B, int E,
                        int* __restrict__ bbase, int* __restrict__ cursor){
  __shared__ int s[512];
  int t=threadIdx.x;
  int v=(t<B)?bcnt[t]:0;
  s[t]=v; __syncthreads();
  for(int off=1;off<512;off<<=1){ int u=(t>=off)?s[t-off]:0; __syncthreads(); s[t]+=u; __syncthreads(); }
  if(t<B){ bbase[t]=s[t]-v; cursor[t]=s[t]-v; }
  if(t==0) bbase[B]=E;
}

// ---- binning body: stg[...] = (local<<24 | row, ew), grouped by bucket ----
__device__ __forceinline__ void bfill_body(const int* __restrict__ row, const int* __restrict__ col,
    const float* __restrict__ ew, int E, int* __restrict__ cursor, uint2* __restrict__ stg,
    int bid, char* smem){
  int* h  =(int*)smem;
  int* ofs=h+512;
  int t=threadIdx.x;
  for(int i=t;i<512;i+=256) h[i]=0;
  __syncthreads();
  int e0=bid*4096, e1=min(e0+4096,E);
  for(int e=e0+t;e<e1;e+=256) atomicAdd(&h[((unsigned)col[e])>>8],1);
  __syncthreads();
  for(int i=t;i<512;i+=256) ofs[i] = h[i] ? atomicAdd(&cursor[i],h[i]) : 0;
  __syncthreads();
  for(int i=t;i<512;i+=256) h[i]=0;
  __syncthreads();
  for(int e=e0+t;e<e1;e+=256){
    unsigned d=(unsigned)col[e];
    int b=d>>8;
    int lp=atomicAdd(&h[b],1);
    stg[ofs[b]+lp]=make_uint2(((d&255u)<<24)|(unsigned)row[e], __float_as_uint(ew[e]));
  }
}

// ---- per-bucket: degree -> dnorm + rowptr (LDS count + scan) ----
__global__ __launch_bounds__(256) void k_p2a(const uint2* __restrict__ stg, const int* __restrict__ bbase,
    int N, int E, float* __restrict__ dnorm, int* __restrict__ rowptr){
  __shared__ int cnt[256];
  __shared__ int pre[256];
  int b=blockIdx.x, t=threadIdx.x;
  cnt[t]=0; __syncthreads();
  int s0=bbase[b], s1=bbase[b+1];
  for(int p=s0+t;p<s1;p+=256) atomicAdd(&cnt[stg[p].x>>24],1);
  __syncthreads();
  int v=cnt[t];
  pre[t]=v; __syncthreads();
  for(int off=1;off<256;off<<=1){ int u=(t>=off)?pre[t-off]:0; __syncthreads(); pre[t]+=u; __syncthreads(); }
  int node=(b<<8)+t;
  if(node<N){
    dnorm[node]= v>0 ? rsqrtf((float)v) : 0.f;   // nan_to_num: deg==0 -> coefficient 0
    rowptr[node]=s0+pre[t]-v;
    if(node==N-1) rowptr[N]=E;
  }
}

// ---- per-bucket: place records -> pairs, folding dnorm[row] into the value ----
__global__ __launch_bounds__(256) void k_p2b(const uint2* __restrict__ stg, const int* __restrict__ bbase,
    int N, const int* __restrict__ rowptr, const float* __restrict__ dnorm,
    float2* __restrict__ pairs){
  __shared__ int cur[256];
  int b=blockIdx.x, t=threadIdx.x;
  int node=(b<<8)+t;
  cur[t]=(node<N)?rowptr[node]:0;
  __syncthreads();
  int s0=bbase[b], s1=bbase[b+1];
  for(int p=s0+t;p<s1;p+=256){
    uint2 rec=stg[p];
    int r=(int)(rec.x&0xFFFFFFu);
    int pos=atomicAdd(&cur[rec.x>>24],1);
    pairs[pos]=make_float2(__int_as_float(r), __uint_as_float(rec.y)*dnorm[r]);
  }
}

// ---------------- SpMM bf16: wave/dest, 2 cols/lane, 16 gathers in flight ----------------
// Proven v8 body (60.6us; best of 4 structural attempts — do not touch). Edge
// bookkeeping is fully scalar: pairs loads are wave-uniform s_load; gather = SGPR base
// + fixed lane offset; weight is an SGPR fma operand. v10 lesson: per-lane edge
// addressing doubles VALU time. v11 lesson: masked-full-batch tail adds ~50% edge work.
// BN0 applies stage-0 BN+ReLU inline to each gathered value (gather source = raw z0).
template<bool BN0>
__global__ __launch_bounds__(256) void k_spmm_bf(const float2* __restrict__ pairs,
    const int* __restrict__ rowptr, const float* __restrict__ dnorm,
    const unsigned short* __restrict__ hb, unsigned short* __restrict__ zb, int N,
    const float* __restrict__ bnst, const float* __restrict__ gamma,
    const float* __restrict__ beta, float invN){
  int wid=(blockIdx.x*256+threadIdx.x)>>6;
  int lane=threadIdx.x&63;
  if(wid>=N) return;
  float sc0=0.f,sh0=0.f,sc1=0.f,sh1=0.f;
  if(BN0){
    int c0=lane<<1;
    float m0=bnst[c0]*invN,      m1=bnst[c0+1]*invN;
    float v0=bnst[128+c0]*invN-m0*m0, v1=bnst[129+c0]*invN-m1*m1;
    sc0=rsqrtf(v0+EPS)*gamma[c0];   sh0=beta[c0]-m0*sc0;
    sc1=rsqrtf(v1+EPS)*gamma[c0+1]; sh1=beta[c0+1]-m1*sc1;
  }
  int beg=__builtin_amdgcn_readfirstlane(rowptr[wid]);
  int end=__builtin_amdgcn_readfirstlane(rowptr[wid+1]);
  float ax=0.f, ay=0.f;
  int p=beg;
  for(; p+16<=end; p+=16){
    float2 pr[16]; unsigned int u[16];
    #pragma unroll
    for(int j=0;j<16;j++) pr[j]=pairs[p+j];
    #pragma unroll
    for(int j=0;j<16;j++)
      u[j]=*(const unsigned int*)(hb + (((size_t)__float_as_int(pr[j].x))<<7) + (lane<<1));
    #pragma unroll
    for(int j=0;j<16;j++){
      float f0=bflo(u[j]), f1=bfhi(u[j]);
      if(BN0){ f0=fmaxf(fmaf(f0,sc0,sh0),0.f); f1=fmaxf(fmaf(f1,sc1,sh1),0.f); }
      ax=fmaf(pr[j].y,f0,ax); ay=fmaf(pr[j].y,f1,ay);
    }
  }
  for(; p+4<=end; p+=4){
    float2 pr[4]; unsigned int u[4];
    #pragma unroll
    for(int j=0;j<4;j++) pr[j]=pairs[p+j];
    #pragma unroll
    for(int j=0;j<4;j++)
      u[j]=*(const unsigned int*)(hb + (((size_t)__float_as_int(pr[j].x))<<7) + (lane<<1));
    #pragma unroll
    for(int j=0;j<4;j++){
      float f0=bflo(u[j]), f1=bfhi(u[j]);
      if(BN0){ f0=fmaxf(fmaf(f0,sc0,sh0),0.f); f1=fmaxf(fmaf(f1,sc1,sh1),0.f); }
      ax=fmaf(pr[j].y,f0,ax); ay=fmaf(pr[j].y,f1,ay);
    }
  }
  for(; p<end; ++p){
    float2 pr=pairs[p];
    unsigned int u=*(const unsigned int*)(hb + (((size_t)__float_as_int(pr.x))<<7) + (lane<<1));
    float f0=bflo(u), f1=bfhi(u);
    if(BN0){ f0=fmaxf(fmaf(f0,sc0,sh0),0.f); f1=fmaxf(fmaf(f1,sc1,sh1),0.f); }
    ax=fmaf(pr.y,f0,ax); ay=fmaf(pr.y,f1,ay);
  }
  float dn=dnorm[wid];
  *(unsigned int*)(zb + ((size_t)wid<<7) + (lane<<1)) = pack_bf16(ax*dn, ay*dn);
}

// ---------------- MFMA GEMM body (128 rows/block @ 128x128) + fused BN sum/sumsq ----------------
// W pre-transposed bf16 in global -> staging is a pure 16B-vector copy. In-place safe:
// each block reads exactly the rows it writes. Layouts: A m=lane&15,k=quad*8+j;
// C/D col=lane&15, row=quad*4+reg [m89/m120-verified].
template<bool F32A>
__device__ __forceinline__ void gemm_bn_body(const void* __restrict__ Ap,
    const unsigned short* __restrict__ Wt, const float* __restrict__ bias,
    unsigned short* __restrict__ Zb, float* __restrict__ stats, int N,
    int bid, char* smem){
  unsigned short* sWT=(unsigned short*)smem;              // 34816 B
  int t=threadIdx.x;

  {
    const uint4* gw=(const uint4*)Wt;                     // 2176 x 16B
    uint4* sw=(uint4*)sWT;
    #pragma unroll
    for(int it=0; it<8; it++) sw[t + it*256] = gw[t + it*256];
    if(t<128) sw[2048+t]=gw[2048+t];
  }
  __syncthreads();

  int w=t>>6, lane=t&63, n=lane&15, quad=lane>>4;
  int r0w = bid*128 + w*32;

  f32x4 acc[8][2];
  #pragma unroll
  for(int nt=0;nt<8;nt++)
    #pragma unroll
    for(int rt=0;rt<2;rt++){ f32x4 z4={0.f,0.f,0.f,0.f}; acc[nt][rt]=z4; }

  #pragma unroll
  for(int ks=0; ks<4; ks++){
    int k0 = ks*32 + quad*8;
    bf16x8 a[2];
    #pragma unroll
    for(int rt=0;rt<2;rt++){
      int r = r0w + rt*16 + n;
      bf16x8 af={0,0,0,0,0,0,0,0};
      if(r<N){
        if(F32A){
          const float* Af=(const float*)Ap;
          float4 u0=*(const float4*)&Af[(size_t)r*128 + k0];
          float4 u1=*(const float4*)&Af[(size_t)r*128 + k0 + 4];
          af[0]=(short)f2bf(u0.x); af[1]=(short)f2bf(u0.y);
          af[2]=(short)f2bf(u0.z); af[3]=(short)f2bf(u0.w);
          af[4]=(short)f2bf(u1.x); af[5]=(short)f2bf(u1.y);
          af[6]=(short)f2bf(u1.z); af[7]=(short)f2bf(u1.w);
        }else{
          af = *(const bf16x8*)((const unsigned short*)Ap + (size_t)r*128 + k0);
        }
      }
      a[rt]=af;
    }
    #pragma unroll
    for(int nt=0;nt<8;nt++){
      bf16x8 b = *(const bf16x8*)&sWT[(nt*16+n)*136 + k0];
      #pragma unroll
      for(int rt=0;rt<2;rt++)
        acc[nt][rt]=__builtin_amdgcn_mfma_f32_16x16x32_bf16(a[rt], b, acc[nt][rt], 0,0,0);
    }
  }

  __syncthreads();                        // reuse smem for stats partials
  float* sS=(float*)smem;                 // [16][132]
  float* sQ=sS + 16*132;                  // [16][132]
  #pragma unroll
  for(int nt=0;nt<8;nt++){
    int c=nt*16+n;
    float bc=bias[c];
    float s=0.f,q=0.f;
    #pragma unroll
    for(int rt=0;rt<2;rt++){
      #pragma unroll
      for(int i=0;i<4;i++){
        int r=r0w + rt*16 + quad*4 + i;
        if(r<N){
          float z=acc[nt][rt][i]+bc;
          Zb[(size_t)r*128+c]=f2bf(z);
          s+=z; q+=z*z;
        }
      }
    }
    sS[(w*4+quad)*132+c]=s;
    sQ[(w*4+quad)*132+c]=q;
  }
  __syncthreads();
  if(t<128){
    float s=0.f,q=0.f;
    #pragma unroll
    for(int g=0;g<16;g++){ s+=sS[g*132+t]; q+=sQ[g*132+t]; }
    atomicAdd(&stats[t],s); atomicAdd(&stats[128+t],q);
  }
}

// ---- standalone GEMM kernel (layers 1 & 2, bf16 A) ----
template<bool F32A>
__global__ __launch_bounds__(256,3) void k_gemm_bn(const void* __restrict__ Ap,
    const unsigned short* __restrict__ Wt, const float* __restrict__ bias,
    unsigned short* __restrict__ Zb, float* __restrict__ stats, int N){
  __shared__ __align__(16) char smem[34816];
  gemm_bn_body<F32A>(Ap, Wt, bias, Zb, stats, N, blockIdx.x, smem);
}

// ---- packed: [gemm1 (GB blocks, f32 A) | bfill] — independent, disjoint I/O ----
__global__ __launch_bounds__(256,3) void k_g1bf(const float* __restrict__ x,
    const unsigned short* __restrict__ Wt, const float* __restrict__ bias,
    unsigned short* __restrict__ Zb, float* __restrict__ stats, int N, int GB,
    const int* __restrict__ row, const int* __restrict__ col,
    const float* __restrict__ ew, int E, int* __restrict__ cursor,
    uint2* __restrict__ stg){
  __shared__ __align__(16) char smem[34816];
  int bid=blockIdx.x;
  if(bid<GB) gemm_bn_body<true>(x, Wt, bias, Zb, stats, N, bid, smem);
  else       bfill_body(row, col, ew, E, cursor, stg, bid-GB, smem);
}

// ---------------- apply: BN finalize (in-block) + scale/shift + ReLU + residual ----------------
// 16 B/lane (8 ch). BNRES: residual operand is raw z0 -> apply stage-0 BN+ReLU inline
// (h0 never materialized). smi[0:256)=this stage scale/shift, smi[256:512)=residual's.
template<bool OUTF32, bool BNRES>
__global__ __launch_bounds__(256) void k_apply(const unsigned short* __restrict__ Zb,
    const float* __restrict__ stats, const float* __restrict__ gamma,
    const float* __restrict__ beta, float invN,
    const unsigned short* __restrict__ res,
    const float* __restrict__ rstats, const float* __restrict__ rgamma,
    const float* __restrict__ rbeta,
    float* __restrict__ outf, unsigned short* __restrict__ outb, int n16){
  __shared__ float smi[512];
  int t=threadIdx.x;
  if(t<128){
    float mean=stats[t]*invN;
    float var=stats[128+t]*invN - mean*mean;
    float sc=rsqrtf(var+EPS)*gamma[t];
    smi[t]=sc; smi[128+t]=beta[t]-mean*sc;
    if(BNRES){
      float rm=rstats[t]*invN;
      float rv=rstats[128+t]*invN - rm*rm;
      float rs=rsqrtf(rv+EPS)*rgamma[t];
      smi[256+t]=rs; smi[384+t]=rbeta[t]-rm*rs;
    }
  }
  __syncthreads();
  int i=blockIdx.x*256+t;
  if(i>=n16) return;
  int c=(i&15)*8;
  uint4 zu=((const uint4*)Zb)[i];
  float z[8]={bflo(zu.x),bfhi(zu.x),bflo(zu.y),bfhi(zu.y),
              bflo(zu.z),bfhi(zu.z),bflo(zu.w),bfhi(zu.w)};
  float o[8];
  #pragma unroll
  for(int k=0;k<8;k++) o[k]=fmaxf(fmaf(z[k],smi[c+k],smi[128+c+k]),0.f);
  if(res){
    uint4 ru=((const uint4*)res)[i];
    float r[8]={bflo(ru.x),bfhi(ru.x),bflo(ru.y),bfhi(ru.y),
                bflo(ru.z),bfhi(ru.z),bflo(ru.w),bfhi(ru.w)};
    if(BNRES){
      #pragma unroll
      for(int k=0;k<8;k++) r[k]=fmaxf(fmaf(r[k],smi[256+c+k],smi[384+c+k]),0.f);
    }
    #pragma unroll
    for(int k=0;k<8;k++) o[k]+=r[k];
  }
  if(OUTF32){
    float4 oa={o[0],o[1],o[2],o[3]}, ob={o[4],o[5],o[6],o[7]};
    ((float4*)outf)[2*i]  =oa;
    ((float4*)outf)[2*i+1]=ob;
  }else{
    uint4 pk;
    pk.x=pack_bf16(o[0],o[1]); pk.y=pack_bf16(o[2],o[3]);
    pk.z=pack_bf16(o[4],o[5]); pk.w=pack_bf16(o[6],o[7]);
    ((uint4*)outb)[i]=pk;
  }
}

extern "C" void kernel_launch(void* const* d_in, const int* in_sizes, int n_in,
                              void* d_out, int out_size, void* d_ws, size_t ws_size,
                              hipStream_t stream){
  const float* x      = (const float*)d_in[0];
  const int*   ei     = (const int*)  d_in[1];
  const float* ew     = (const float*)d_in[2];
  const float* fc_w   = (const float*)d_in[3];
  const float* fc_b   = (const float*)d_in[4];
  const float* conv_w = (const float*)d_in[5];
  const float* conv_b = (const float*)d_in[6];
  const float* gamma  = (const float*)d_in[7];
  const float* beta   = (const float*)d_in[8];
  float* out = (float*)d_out;

  int N = in_sizes[0]/H;
  int E = in_sizes[2];
  const int* row = ei;
  const int* col = ei + E;
  int B = (N+NPB-1)/NPB;                 // buckets

  // workspace layout (~78 MB)
  size_t NH = (size_t)N*H;
  unsigned short* Wt   = (unsigned short*)d_ws;  // 3*17408 bf16 (pitch-136 WT), 104448 B
  unsigned short* zb   = Wt + 3*17408;           // N*H bf16: z0, then h1
  unsigned short* hbuf = zb + NH;                // N*H bf16: agg / z1 / z2
  uint2*  stg    = (uint2*)(hbuf + NH);          // E bucket-grouped records
  float2* pairs  = (float2*)(stg + E);           // E final CSR records (val = ew*dnorm[row])
  float*  stats  = (float*)(pairs + E);          // 3*256   } contiguous for
  int*    bcnt   = (int*)(stats + 768);          // 512     } single memset
  int*    bbase  = bcnt + 512;                   // 513
  int*    cursor = bbase + 513;                  // 512
  float*  dnorm  = (float*)(cursor + 512);       // N
  int*    rowptr = (int*)(dnorm + N);            // N+1

  hipMemsetAsync(stats, 0, sizeof(float)*(768+512), stream);

  int gE4k = (E+4095)/4096;
  int GB=(N+127)/128;

  // packed: wconv (192) | bcount (gE4k)
  k_wb<<<192+gE4k,256,0,stream>>>(fc_w, conv_w, Wt, 192, col, E, bcnt);
  k_bscan<<<1,512,0,stream>>>(bcnt,B,E,bbase,cursor);
  // packed: gemm1 z0 = x@fc_w+fc_b (GB blocks) | bfill (gE4k) — independent
  k_g1bf<<<GB+gE4k,256,0,stream>>>(x, Wt, fc_b, zb, stats, N, GB,
                                   row, col, ew, E, cursor, stg);
  k_p2a<<<B,256,0,stream>>>(stg,bbase,N,E,dnorm,rowptr);
  k_p2b<<<B,256,0,stream>>>(stg,bbase,N,rowptr,dnorm,pairs);

  int gApply=((N*16)+255)/256;
  int gSpmm=(N+3)/4;
  float invN=1.f/(float)N;

  // layer 0: agg = A_hat @ relu(bn0(z0))  [BN0 inline in gather]  -> hbuf
  k_spmm_bf<true><<<gSpmm,256,0,stream>>>(pairs,rowptr,dnorm, zb, hbuf, N,
                                          stats, gamma, beta, invN);
  k_gemm_bn<false><<<GB,256,0,stream>>>(hbuf, Wt+17408, conv_b, hbuf, stats+256, N);
  // h1 = relu(bn1(z1)) + relu(bn0(z0))  -> zb (in-place over z0)
  k_apply<false,true><<<gApply,256,0,stream>>>(hbuf, stats+256, gamma+H, beta+H, invN,
                                               zb, stats, gamma, beta,
                                               nullptr, zb, N*16);

  // layer 1: out = relu(bn2(agg(h1) @ W1 + b1)) + h1 -> fp32 d_out
  k_spmm_bf<false><<<gSpmm,256,0,stream>>>(pairs,rowptr,dnorm, zb, hbuf, N,
                                           nullptr, nullptr, nullptr, 0.f);
  k_gemm_bn<false><<<GB,256,0,stream>>>(hbuf, Wt+2*17408, conv_b+H, hbuf, stats+512, N);
  k_apply<true,false><<<gApply,256,0,stream>>>(hbuf, stats+512, gamma+2*H, beta+2*H, invN,
                                               zb, nullptr, nullptr, nullptr,
                                               out, nullptr, N*16);
}